// Round 10
// baseline (115.225 us; speedup 1.0000x reference)
//
#include <hip/hip_runtime.h>

typedef __attribute__((ext_vector_type(4))) int  i32x4;
typedef __attribute__((ext_vector_type(16))) int i32x16;
typedef __attribute__((ext_vector_type(2))) float f32x2;

#define IC   256
#define OCH  128
#define BSZ  16
#define IH   64
#define IW   64
#define OH2  128
#define OW2  128
#define QMAXF 127.0f

// ws float-offset layout
#define WS_WSCALE 0        // 256 per-ic weight absmax
#define WS_APART  256      // 8*256 per-(bq,ic) act absmax partials
#define WS_QS     2304     // 256: x multiplier 1/(sc*sx)
#define WS_F      2816     // sx*sw
#define WS_WQ8    3072     // int8 [9][16][128][16] quantized weights (294912 B)

// ---------------- K1: per-channel absmax (partials over batch) ----------------
__global__ __launch_bounds__(256) void k_channel_scales(
        const float* __restrict__ x, const float* __restrict__ w,
        float* __restrict__ ws) {
    const int ic = blockIdx.x;
    const int bq = blockIdx.y;          // 0..7, two batches each
    const int t  = threadIdx.x;
    float amax = 0.f, wmax = 0.f;
    for (int bb = 2 * bq; bb < 2 * bq + 2; ++bb) {
        const float* xp = x + ((size_t)(bb * IC + ic)) * (IH * IW);
        for (int hw = t * 4; hw < IH * IW; hw += 1024) {
            float4 v = *(const float4*)(xp + hw);
            amax = fmaxf(amax, fmaxf(fmaxf(fabsf(v.x), fabsf(v.y)),
                                     fmaxf(fabsf(v.z), fabsf(v.w))));
        }
    }
    if (bq == 0)
        for (int j = t; j < OCH * 9; j += 256)
            wmax = fmaxf(wmax, fabsf(w[ic * (OCH * 9) + j]));
    __shared__ float r1[256], r2[256];
    r1[t] = wmax; r2[t] = amax;
    __syncthreads();
    for (int s = 128; s > 0; s >>= 1) {
        if (t < s) {
            r1[t] = fmaxf(r1[t], r1[t + s]);
            r2[t] = fmaxf(r2[t], r2[t + s]);
        }
        __syncthreads();
    }
    if (t == 0) {
        ws[WS_APART + bq * 256 + ic] = r2[0];
        if (bq == 0) ws[WS_WSCALE + ic] = r1[0];
    }
}

// ---- K2: finalize scales (redundant per block) + quantize weights -> int8 ----
// wq8 layout: [tap][kq(16)][oc(128)][16B]
__global__ __launch_bounds__(256) void k_quant_w(
        const float* __restrict__ w, float* __restrict__ ws) {
    __shared__ float scs[256], r1[256], r2[256];
    const int t = threadIdx.x;          // = ic for the scale phase
    float asc = 0.f;
    #pragma unroll
    for (int q8 = 0; q8 < 8; ++q8) asc = fmaxf(asc, ws[WS_APART + q8 * 256 + t]);
    const float wsc = ws[WS_WSCALE + t];
    float sc = sqrtf(asc) / sqrtf(wsc);
    if (sc == 0.f) sc = 1.f;
    r1[t] = wsc * sc;                   // elementwise max of |w*sc| (monotone)
    r2[t] = asc / sc;                   // elementwise max of |x/sc|
    __syncthreads();
    for (int s = 128; s > 0; s >>= 1) {
        if (t < s) {
            r1[t] = fmaxf(r1[t], r1[t + s]);
            r2[t] = fmaxf(r2[t], r2[t + s]);
        }
        __syncthreads();
    }
    float sw = r1[0] / QMAXF; if (sw == 0.f) sw = 1.f;
    float sx = r2[0] / QMAXF; if (sx == 0.f) sx = 1.f;
    scs[t] = sc / sw;                   // weight multiplier
    if (blockIdx.x == 0) {
        ws[WS_QS + t] = 1.f / (sc * sx);
        if (t == 0) ws[WS_F] = sx * sw;
    }
    __syncthreads();

    const int idx = blockIdx.x * 256 + t;   // [tap][kq][oc][e4]
    const int e0  = (idx & 3) * 4;
    const int oc  = (idx >> 2) & 127;
    const int kq  = (idx >> 9) & 15;
    const int tap = idx >> 13;
    unsigned pack = 0;
    #pragma unroll
    for (int c = 0; c < 4; ++c) {
        const int ic = kq * 16 + e0 + c;
        float q = rintf(w[((size_t)ic * OCH + oc) * 9 + tap] * scs[ic]);
        q = fminf(fmaxf(q, -128.f), 127.f);
        pack |= ((unsigned)((int)q & 255)) << (8 * c);
    }
    ((unsigned*)(ws + WS_WQ8))[idx] = pack;
}

// ---------------- K3: MFMA implicit-GEMM conv, swapped operands ----------------
// A-tile int8 [r(2)][v(66)][ic(256)], byte = (r*66+v)*256 + (ic ^ ((v&15)<<4))
__device__ __forceinline__ i32x4 load_a(const char* qa, int R, int S, int ks, int m, int lane) {
    const int v = m * 32 + (lane & 31) + S;
    const unsigned byte = (unsigned)((R * 66 + v) * 256)
        + (((unsigned)(ks * 32 + ((lane >> 5) << 4))) ^ (((unsigned)(v & 15)) << 4));
    return *(const i32x4*)(qa + byte);
}

__device__ __forceinline__ i32x4 load_b(const char* wq8, int tap, int ks, int oc, int lane) {
    const size_t off = ((size_t)((tap * 16 + ks * 2 + (lane >> 5)) * OCH + oc)) * 16;
    return *(const i32x4*)(wq8 + off);
}

// batch all 8 B-loads of a tap into registers first (8 in flight), then MFMA
template<int NT>
__device__ __forceinline__ void gemm_run(const char* qa, const char* wq8,
        const int (&taps)[NT], int oc0, int lane, i32x16 (&acc)[2]) {
    #pragma unroll
    for (int t = 0; t < NT; ++t) {
        const int tap = taps[t];
        const int R = tap < 3 ? 1 : 0;
        const int S = (tap % 3 == 0) ? 1 : 0;
        i32x4 bb[8];
        #pragma unroll
        for (int ks = 0; ks < 8; ++ks)
            bb[ks] = load_b(wq8, tap, ks, oc0, lane);
        #pragma unroll
        for (int ks = 0; ks < 8; ++ks) {
            const i32x4 a0 = load_a(qa, R, S, ks, 0, lane);
            const i32x4 a1 = load_a(qa, R, S, ks, 1, lane);
            // swapped: weights are the M-operand -> D has row=oc, col=v
            acc[0] = __builtin_amdgcn_mfma_i32_32x32x32_i8(bb[ks], a0, acc[0], 0, 0, 0);
            acc[1] = __builtin_amdgcn_mfma_i32_32x32x32_i8(bb[ks], a1, acc[1], 0, 0, 0);
        }
    }
}

__global__ __launch_bounds__(256) void k_conv(
        const float* __restrict__ x, const float* __restrict__ bias,
        const float* __restrict__ ws, float* __restrict__ out) {
    __shared__ __align__(16) char smem[33792 + 512];
    char*  qa    = smem;
    float* sbias = (float*)(smem + 33792);

    const int tid  = threadIdx.x;
    // bijective XCD swizzle (1024 % 8 == 0): each XCD gets 128 consecutive f
    const int f0   = (blockIdx.x & 7) * 128 + (blockIdx.x >> 3);
    const int b    = f0 >> 6;
    const int u    = f0 & 63;        // output rows 2u, 2u+1
    const int lane = tid & 63;
    const int q    = tid >> 6;       // wave = oc quarter (32 wide), 0..3

    // zero pad column v=64 (both r); load bias to LDS
    if (tid < 128)
        ((int*)(qa + ((tid >> 6) * 66 + 64) * 256))[tid & 63] = 0;
    else
        sbias[tid - 128] = bias[tid - 128];

    // stage + quantize x rows u, u+1 -> int8 LDS (lane <-> col, coalesced);
    // per-iteration scale factors are wave-uniform -> s_loads
    for (int j = tid; j < 8192; j += 256) {
        const int v   = j & 63;
        const int icq = (j >> 6) & 63;
        const int rr  = j >> 12;
        const int row = u + rr;
        const int ic0 = icq * 4;
        unsigned pack = 0;
        if (row < IH) {
            const float* xp = x + (((size_t)(b * IC + ic0)) * IH + row) * IW + v;
            #pragma unroll
            for (int c = 0; c < 4; ++c) {
                float qv = fminf(fmaxf(rintf(xp[(size_t)c * IH * IW] * ws[WS_QS + ic0 + c]),
                                       -128.f), 127.f);
                pack |= ((unsigned)((int)qv & 255)) << (8 * c);
            }
        }
        *(unsigned*)(qa + (rr * 66 + v) * 256 + ((unsigned)ic0 ^ (((unsigned)(v & 15)) << 4))) = pack;
    }
    __syncthreads();                 // the ONLY barrier

    const char* wq8 = (const char*)(ws + WS_WQ8);
    const int oc0 = q * 32 + (lane & 31);
    const float fsc = ws[WS_F];
    const int vv  = lane & 31;
    const int ocq = q * 32 + 4 * (lane >> 5);

    // dense f32x2 NT stores: lane&31 = v, both parities in-lane -> ow {2v, 2v+1}
    auto store_row = [&](const i32x16 (&p0)[2], const i32x16 (&p1)[2], int oh) {
        #pragma unroll
        for (int reg = 0; reg < 16; ++reg) {
            const int oc = ocq + (reg & 3) + 8 * (reg >> 2);
            const float bv = sbias[oc];
            float* rowp = out + (((size_t)(b * OCH + oc)) * OH2 + oh) * OW2;
            #pragma unroll
            for (int m = 0; m < 2; ++m) {
                f32x2 o;
                o.x = fmaf((float)p0[m][reg], fsc, bv);
                o.y = fmaf((float)p1[m][reg], fsc, bv);
                __builtin_nontemporal_store(o, (f32x2*)(rowp + 2 * (m * 32 + vv)));
            }
        }
    };

    i32x16 accP0[2], accP1[2];       // 64 VGPR accumulator budget (spill-free shape)

    // ---- output row 2u: par0 tap{4}, par1 taps{3,5} ----
    accP0[0] = (i32x16)(0); accP0[1] = (i32x16)(0);
    accP1[0] = (i32x16)(0); accP1[1] = (i32x16)(0);
    {
        const int t0[1] = {4};
        gemm_run<1>(qa, wq8, t0, oc0, lane, accP0);
        const int t1[2] = {3, 5};
        gemm_run<2>(qa, wq8, t1, oc0, lane, accP1);
    }
    store_row(accP0, accP1, 2 * u);

    // ---- output row 2u+1: par0 taps{1,7}, par1 taps{0,2,6,8} ----
    accP0[0] = (i32x16)(0); accP0[1] = (i32x16)(0);
    accP1[0] = (i32x16)(0); accP1[1] = (i32x16)(0);
    {
        const int t0[2] = {1, 7};
        gemm_run<2>(qa, wq8, t0, oc0, lane, accP0);
        const int t1[4] = {0, 2, 6, 8};
        gemm_run<4>(qa, wq8, t1, oc0, lane, accP1);
    }
    store_row(accP0, accP1, 2 * u + 1);
}

extern "C" void kernel_launch(void* const* d_in, const int* in_sizes, int n_in,
                              void* d_out, int out_size, void* d_ws, size_t ws_size,
                              hipStream_t stream) {
    const float* x    = (const float*)d_in[0];
    const float* w    = (const float*)d_in[1];
    const float* bias = (const float*)d_in[2];
    float* ws  = (float*)d_ws;
    float* out = (float*)d_out;

    k_channel_scales<<<dim3(256, 8), 256, 0, stream>>>(x, w, ws);
    k_quant_w<<<288, 256, 0, stream>>>(w, ws);
    k_conv<<<1024, 256, 0, stream>>>(x, bias, ws, out);
}

// Round 11
// 79.557 us; speedup vs baseline: 1.4483x; 1.4483x over previous
//
#include <hip/hip_runtime.h>

typedef __attribute__((ext_vector_type(4))) int  i32x4;
typedef __attribute__((ext_vector_type(16))) int i32x16;
typedef __attribute__((ext_vector_type(2))) float f32x2;

#define IC   256
#define OCH  128
#define BSZ  16
#define IH   64
#define IW   64
#define OH2  128
#define OW2  128
#define QMAXF 127.0f

// ws float-offset layout
#define WS_WSCALE 0        // 256 per-ic weight absmax
#define WS_APART  256      // 8*256 per-(bq,ic) act absmax partials
#define WS_QS     2304     // 256: x multiplier 1/(sc*sx)
#define WS_F      2816     // sx*sw
#define WS_WQ8    3072     // int8 [9][16][128][16] quantized weights (294912 B)
#define WS_QX     76800    // int8 [16][64][64][256] pre-swizzled quantized x (16.78 MB)

// ---------------- K1: per-channel absmax (partials over batch) ----------------
__global__ __launch_bounds__(256) void k_channel_scales(
        const float* __restrict__ x, const float* __restrict__ w,
        float* __restrict__ ws) {
    const int ic = blockIdx.x;
    const int bq = blockIdx.y;          // 0..7, two batches each
    const int t  = threadIdx.x;
    float amax = 0.f, wmax = 0.f;
    for (int bb = 2 * bq; bb < 2 * bq + 2; ++bb) {
        const float* xp = x + ((size_t)(bb * IC + ic)) * (IH * IW);
        for (int hw = t * 4; hw < IH * IW; hw += 1024) {
            float4 v = *(const float4*)(xp + hw);
            amax = fmaxf(amax, fmaxf(fmaxf(fabsf(v.x), fabsf(v.y)),
                                     fmaxf(fabsf(v.z), fabsf(v.w))));
        }
    }
    if (bq == 0)
        for (int j = t; j < OCH * 9; j += 256)
            wmax = fmaxf(wmax, fabsf(w[ic * (OCH * 9) + j]));
    __shared__ float r1[256], r2[256];
    r1[t] = wmax; r2[t] = amax;
    __syncthreads();
    for (int s = 128; s > 0; s >>= 1) {
        if (t < s) {
            r1[t] = fmaxf(r1[t], r1[t + s]);
            r2[t] = fmaxf(r2[t], r2[t + s]);
        }
        __syncthreads();
    }
    if (t == 0) {
        ws[WS_APART + bq * 256 + ic] = r2[0];
        if (bq == 0) ws[WS_WSCALE + ic] = r1[0];
    }
}

// ---- K2: finalize scales (redundant per block) + quantize weights -> int8 ----
// wq8 layout: [tap][kq(16)][oc(128)][16B]
__global__ __launch_bounds__(256) void k_quant_w(
        const float* __restrict__ w, float* __restrict__ ws) {
    __shared__ float scs[256], r1[256], r2[256];
    const int t = threadIdx.x;          // = ic for the scale phase
    float asc = 0.f;
    #pragma unroll
    for (int q8 = 0; q8 < 8; ++q8) asc = fmaxf(asc, ws[WS_APART + q8 * 256 + t]);
    const float wsc = ws[WS_WSCALE + t];
    float sc = sqrtf(asc) / sqrtf(wsc);
    if (sc == 0.f) sc = 1.f;
    r1[t] = wsc * sc;                   // elementwise max of |w*sc| (monotone)
    r2[t] = asc / sc;                   // elementwise max of |x/sc|
    __syncthreads();
    for (int s = 128; s > 0; s >>= 1) {
        if (t < s) {
            r1[t] = fmaxf(r1[t], r1[t + s]);
            r2[t] = fmaxf(r2[t], r2[t + s]);
        }
        __syncthreads();
    }
    float sw = r1[0] / QMAXF; if (sw == 0.f) sw = 1.f;
    float sx = r2[0] / QMAXF; if (sx == 0.f) sx = 1.f;
    scs[t] = sc / sw;                   // weight multiplier
    if (blockIdx.x == 0) {
        ws[WS_QS + t] = 1.f / (sc * sx);
        if (t == 0) ws[WS_F] = sx * sw;
    }
    __syncthreads();

    const int idx = blockIdx.x * 256 + t;   // [tap][kq][oc][e4]
    const int e0  = (idx & 3) * 4;
    const int oc  = (idx >> 2) & 127;
    const int kq  = (idx >> 9) & 15;
    const int tap = idx >> 13;
    unsigned pack = 0;
    #pragma unroll
    for (int c = 0; c < 4; ++c) {
        const int ic = kq * 16 + e0 + c;
        float q = rintf(w[((size_t)ic * OCH + oc) * 9 + tap] * scs[ic]);
        q = fminf(fmaxf(q, -128.f), 127.f);
        pack |= ((unsigned)((int)q & 255)) << (8 * c);
    }
    ((unsigned*)(ws + WS_WQ8))[idx] = pack;
}

// ---- K3: quantize + transpose x ONCE -> qx[b][row][v][ic ^ ((v&15)<<4)] ----
__global__ __launch_bounds__(256) void k_quant_x(
        const float* __restrict__ x, float* __restrict__ ws) {
    __shared__ unsigned tmp[4096];      // [v(64)][64 u32] = 16 KB, pre-swizzled
    const int tid = threadIdx.x;
    const int row = blockIdx.x;
    const int b   = blockIdx.y;
    const int v   = tid & 63;           // lane <-> column, coalesced x reads
    for (int j = tid; j < 4096; j += 256) {
        const int ic0 = ((j >> 6) & 63) * 4;
        const float* xp = x + (((size_t)(b * IC + ic0)) * IH + row) * IW + v;
        unsigned pack = 0;
        #pragma unroll
        for (int c = 0; c < 4; ++c) {
            float qv = fminf(fmaxf(rintf(xp[(size_t)c * IH * IW] * ws[WS_QS + ic0 + c]),
                                   -128.f), 127.f);
            pack |= ((unsigned)((int)qv & 255)) << (8 * c);
        }
        tmp[v * 64 + (((unsigned)ic0 >> 2) ^ (((unsigned)(v & 15)) << 2))] = pack;
    }
    __syncthreads();
    // coalesced 16 KB writeback (stays in L2/L3 for k_conv)
    i32x4* dst = (i32x4*)((char*)(ws + WS_QX) + (((size_t)b * IH + row) * 64) * 256);
    const i32x4* src = (const i32x4*)tmp;
    #pragma unroll
    for (int i = 0; i < 4; ++i)
        dst[i * 256 + tid] = src[i * 256 + tid];
}

// ---------------- K4: MFMA implicit-GEMM conv, swapped operands ----------------
// A-tile int8 [r(2)][v(66)][ic(256)], byte = (r*66+v)*256 + (ic ^ ((v&15)<<4))
__device__ __forceinline__ i32x4 load_a(const char* qa, int R, int S, int ks, int m, int lane) {
    const int v = m * 32 + (lane & 31) + S;
    const unsigned byte = (unsigned)((R * 66 + v) * 256)
        + (((unsigned)(ks * 32 + ((lane >> 5) << 4))) ^ (((unsigned)(v & 15)) << 4));
    return *(const i32x4*)(qa + byte);
}

__device__ __forceinline__ i32x4 load_b(const char* wq8, int tap, int ks, int oc, int lane) {
    const size_t off = ((size_t)((tap * 16 + ks * 2 + (lane >> 5)) * OCH + oc)) * 16;
    return *(const i32x4*)(wq8 + off);
}

template<int NT>
__device__ __forceinline__ void gemm_run(const char* qa, const char* wq8,
        const int (&taps)[NT], int oc0, int lane, i32x16 (&acc)[2]) {
    #pragma unroll
    for (int t = 0; t < NT; ++t) {
        const int tap = taps[t];
        const int R = tap < 3 ? 1 : 0;
        const int S = (tap % 3 == 0) ? 1 : 0;
        #pragma unroll
        for (int ks = 0; ks < 8; ++ks) {
            const i32x4 a0 = load_a(qa, R, S, ks, 0, lane);
            const i32x4 a1 = load_a(qa, R, S, ks, 1, lane);
            const i32x4 bb = load_b(wq8, tap, ks, oc0, lane);
            // swapped: weights are the M-operand -> D has row=oc, col=v
            acc[0] = __builtin_amdgcn_mfma_i32_32x32x32_i8(bb, a0, acc[0], 0, 0, 0);
            acc[1] = __builtin_amdgcn_mfma_i32_32x32x32_i8(bb, a1, acc[1], 0, 0, 0);
        }
    }
}

__global__ __launch_bounds__(256) void k_conv(
        const float* __restrict__ x, const float* __restrict__ bias,
        const float* __restrict__ ws, float* __restrict__ out) {
    __shared__ __align__(16) char smem[33792 + 512];
    char*  qa    = smem;
    float* sbias = (float*)(smem + 33792);

    const int tid  = threadIdx.x;
    // bijective XCD swizzle (1024 % 8 == 0): each XCD gets 128 consecutive f
    const int f0   = (blockIdx.x & 7) * 128 + (blockIdx.x >> 3);
    const int b    = f0 >> 6;
    const int u    = f0 & 63;        // output rows 2u, 2u+1
    const int lane = tid & 63;
    const int q    = tid >> 6;       // wave = oc quarter (32 wide), 0..3

    if (tid < 128) sbias[tid] = bias[tid];
    if (tid < 32) {                  // zero pad column v=64 (both r)
        const int r = tid >> 4;
        *(i32x4*)(qa + (r * 66 + 64) * 256 + (tid & 15) * 16) = (i32x4)(0);
    }

    // staging = pure linear copy of pre-quantized, pre-swizzled rows (16 KB each)
    const char* qx = (const char*)(ws + WS_QX);
    #pragma unroll
    for (int r = 0; r < 2; ++r) {
        const int row = u + r;
        i32x4* dst = (i32x4*)(qa + r * 66 * 256);
        if (row < IH) {
            const i32x4* src = (const i32x4*)(qx + (((size_t)b * IH + row) * 64) * 256);
            #pragma unroll
            for (int i = 0; i < 4; ++i)
                dst[i * 256 + tid] = src[i * 256 + tid];
        } else {
            #pragma unroll
            for (int i = 0; i < 4; ++i)
                dst[i * 256 + tid] = (i32x4)(0);
        }
    }
    __syncthreads();                 // the ONLY barrier

    const char* wq8 = (const char*)(ws + WS_WQ8);
    const int oc0 = q * 32 + (lane & 31);
    const float fsc = ws[WS_F];
    const int vv  = lane & 31;
    const int ocq = q * 32 + 4 * (lane >> 5);

    // dense f32x2 NT stores: lane&31 = v, both parities in-lane -> ow {2v, 2v+1}
    auto store_row = [&](const i32x16 (&p0)[2], const i32x16 (&p1)[2], int oh) {
        #pragma unroll
        for (int reg = 0; reg < 16; ++reg) {
            const int oc = ocq + (reg & 3) + 8 * (reg >> 2);
            const float bv = sbias[oc];
            float* rowp = out + (((size_t)(b * OCH + oc)) * OH2 + oh) * OW2;
            #pragma unroll
            for (int m = 0; m < 2; ++m) {
                f32x2 o;
                o.x = fmaf((float)p0[m][reg], fsc, bv);
                o.y = fmaf((float)p1[m][reg], fsc, bv);
                __builtin_nontemporal_store(o, (f32x2*)(rowp + 2 * (m * 32 + vv)));
            }
        }
    };

    i32x16 accP0[2], accP1[2];       // 64 VGPR accumulator budget (spill-free shape)

    // ---- output row 2u: par0 tap{4}, par1 taps{3,5} ----
    accP0[0] = (i32x16)(0); accP0[1] = (i32x16)(0);
    accP1[0] = (i32x16)(0); accP1[1] = (i32x16)(0);
    {
        const int t0[1] = {4};
        gemm_run<1>(qa, wq8, t0, oc0, lane, accP0);
        const int t1[2] = {3, 5};
        gemm_run<2>(qa, wq8, t1, oc0, lane, accP1);
    }
    store_row(accP0, accP1, 2 * u);

    // ---- output row 2u+1: par0 taps{1,7}, par1 taps{0,2,6,8} ----
    accP0[0] = (i32x16)(0); accP0[1] = (i32x16)(0);
    accP1[0] = (i32x16)(0); accP1[1] = (i32x16)(0);
    {
        const int t0[2] = {1, 7};
        gemm_run<2>(qa, wq8, t0, oc0, lane, accP0);
        const int t1[4] = {0, 2, 6, 8};
        gemm_run<4>(qa, wq8, t1, oc0, lane, accP1);
    }
    store_row(accP0, accP1, 2 * u + 1);
}

extern "C" void kernel_launch(void* const* d_in, const int* in_sizes, int n_in,
                              void* d_out, int out_size, void* d_ws, size_t ws_size,
                              hipStream_t stream) {
    const float* x    = (const float*)d_in[0];
    const float* w    = (const float*)d_in[1];
    const float* bias = (const float*)d_in[2];
    float* ws  = (float*)d_ws;
    float* out = (float*)d_out;

    k_channel_scales<<<dim3(256, 8), 256, 0, stream>>>(x, w, ws);
    k_quant_w<<<288, 256, 0, stream>>>(w, ws);
    k_quant_x<<<dim3(IH, BSZ), 256, 0, stream>>>(x, ws);
    k_conv<<<1024, 256, 0, stream>>>(x, bias, ws, out);
}

// Round 12
// 77.740 us; speedup vs baseline: 1.4822x; 1.0234x over previous
//
#include <hip/hip_runtime.h>

typedef __attribute__((ext_vector_type(4))) int  i32x4;
typedef __attribute__((ext_vector_type(16))) int i32x16;
typedef __attribute__((ext_vector_type(2))) float f32x2;

#define IC   256
#define OCH  128
#define BSZ  16
#define IH   64
#define IW   64
#define OH2  128
#define OW2  128
#define QMAXF 127.0f

// ws float-offset layout
#define WS_WSCALE 0        // 256 per-ic weight absmax
#define WS_APART  256      // 8*256 per-(bq,ic) act absmax partials
#define WS_F      2816     // sx*sw
#define WS_WQ8    3072     // int8 [9][16][128][16] quantized weights (294912 B)
#define WS_QX     76800    // int8 [16][64][64][256] pre-swizzled quantized x (16.78 MB)

// ---------------- K1: per-channel absmax (partials over batch) ----------------
__global__ __launch_bounds__(256) void k_channel_scales(
        const float* __restrict__ x, const float* __restrict__ w,
        float* __restrict__ ws) {
    const int ic = blockIdx.x;
    const int bq = blockIdx.y;          // 0..7, two batches each
    const int t  = threadIdx.x;
    float amax = 0.f, wmax = 0.f;
    for (int bb = 2 * bq; bb < 2 * bq + 2; ++bb) {
        const float* xp = x + ((size_t)(bb * IC + ic)) * (IH * IW);
        for (int hw = t * 4; hw < IH * IW; hw += 1024) {
            float4 v = *(const float4*)(xp + hw);
            amax = fmaxf(amax, fmaxf(fmaxf(fabsf(v.x), fabsf(v.y)),
                                     fmaxf(fabsf(v.z), fabsf(v.w))));
        }
    }
    if (bq == 0)
        for (int j = t; j < OCH * 9; j += 256)
            wmax = fmaxf(wmax, fabsf(w[ic * (OCH * 9) + j]));
    __shared__ float r1[256], r2[256];
    r1[t] = wmax; r2[t] = amax;
    __syncthreads();
    for (int s = 128; s > 0; s >>= 1) {
        if (t < s) {
            r1[t] = fmaxf(r1[t], r1[t + s]);
            r2[t] = fmaxf(r2[t], r2[t + s]);
        }
        __syncthreads();
    }
    if (t == 0) {
        ws[WS_APART + bq * 256 + ic] = r2[0];
        if (bq == 0) ws[WS_WSCALE + ic] = r1[0];
    }
}

// ---- K2 (fused): scale finalize (redundant per block) + w-quant + x-quant ----
// blocks 0..287: wq8[tap][kq(16)][oc(128)][16B]
// blocks 288..1311: qx[b][row][v][ic ^ swz] (pre-swizzled for linear LDS staging)
__global__ __launch_bounds__(256) void k_quant(
        const float* __restrict__ x, const float* __restrict__ w,
        float* __restrict__ ws) {
    __shared__ float scs[256], sqs[256], r1[256], r2[256];
    __shared__ unsigned tmp[4096];      // x-path transpose buffer (16 KB)
    const int t = threadIdx.x;          // = ic for the scale phase
    float asc = 0.f;
    #pragma unroll
    for (int q8 = 0; q8 < 8; ++q8) asc = fmaxf(asc, ws[WS_APART + q8 * 256 + t]);
    const float wsc = ws[WS_WSCALE + t];
    float sc = sqrtf(asc) / sqrtf(wsc);
    if (sc == 0.f) sc = 1.f;
    r1[t] = wsc * sc;                   // elementwise max of |w*sc| (monotone)
    r2[t] = asc / sc;                   // elementwise max of |x/sc|
    __syncthreads();
    for (int s = 128; s > 0; s >>= 1) {
        if (t < s) {
            r1[t] = fmaxf(r1[t], r1[t + s]);
            r2[t] = fmaxf(r2[t], r2[t + s]);
        }
        __syncthreads();
    }
    float sw = r1[0] / QMAXF; if (sw == 0.f) sw = 1.f;
    float sx = r2[0] / QMAXF; if (sx == 0.f) sx = 1.f;
    scs[t] = sc / sw;                   // weight multiplier
    sqs[t] = 1.f / (sc * sx);           // activation multiplier
    if (blockIdx.x == 0 && t == 0) ws[WS_F] = sx * sw;
    __syncthreads();

    if (blockIdx.x < 288) {
        // ---- weight quant path ----
        const int idx = blockIdx.x * 256 + t;   // [tap][kq][oc][e4]
        const int e0  = (idx & 3) * 4;
        const int oc  = (idx >> 2) & 127;
        const int kq  = (idx >> 9) & 15;
        const int tap = idx >> 13;
        unsigned pack = 0;
        #pragma unroll
        for (int c = 0; c < 4; ++c) {
            const int ic = kq * 16 + e0 + c;
            float q = rintf(w[((size_t)ic * OCH + oc) * 9 + tap] * scs[ic]);
            q = fminf(fmaxf(q, -128.f), 127.f);
            pack |= ((unsigned)((int)q & 255)) << (8 * c);
        }
        ((unsigned*)(ws + WS_WQ8))[idx] = pack;
    } else {
        // ---- activation quant + transpose path ----
        const int bid = blockIdx.x - 288;
        const int row = bid & 63;
        const int b   = bid >> 6;
        const int v   = t & 63;         // lane <-> column, coalesced x reads
        for (int j = t; j < 4096; j += 256) {
            const int ic0 = ((j >> 6) & 63) * 4;
            const float* xp = x + (((size_t)(b * IC + ic0)) * IH + row) * IW + v;
            unsigned pack = 0;
            #pragma unroll
            for (int c = 0; c < 4; ++c) {
                float qv = fminf(fmaxf(rintf(xp[(size_t)c * IH * IW] * sqs[ic0 + c]),
                                       -128.f), 127.f);
                pack |= ((unsigned)((int)qv & 255)) << (8 * c);
            }
            tmp[v * 64 + (((unsigned)ic0 >> 2) ^ (((unsigned)(v & 15)) << 2))] = pack;
        }
        __syncthreads();
        // coalesced 16 KB writeback (stays in L2/L3 for k_conv)
        i32x4* dst = (i32x4*)((char*)(ws + WS_QX) + (((size_t)b * IH + row) * 64) * 256);
        const i32x4* src = (const i32x4*)tmp;
        #pragma unroll
        for (int i = 0; i < 4; ++i)
            dst[i * 256 + t] = src[i * 256 + t];
    }
}

// ---------------- K3: MFMA implicit-GEMM conv, swapped operands ----------------
// A-tile int8 [r(2)][v(66)][ic(256)], byte = (r*66+v)*256 + (ic ^ ((v&15)<<4))
__device__ __forceinline__ i32x4 load_a(const char* qa, int R, int S, int ks, int m, int lane) {
    const int v = m * 32 + (lane & 31) + S;
    const unsigned byte = (unsigned)((R * 66 + v) * 256)
        + (((unsigned)(ks * 32 + ((lane >> 5) << 4))) ^ (((unsigned)(v & 15)) << 4));
    return *(const i32x4*)(qa + byte);
}

__device__ __forceinline__ i32x4 load_b(const char* wq8, int tap, int ks, int oc, int lane) {
    const size_t off = ((size_t)((tap * 16 + ks * 2 + (lane >> 5)) * OCH + oc)) * 16;
    return *(const i32x4*)(wq8 + off);
}

// 1-deep software pipeline: prefetch next {b, a0, a1} while current MFMAs issue
template<int NT>
__device__ __forceinline__ void gemm_run(const char* qa, const char* wq8,
        const int (&taps)[NT], int oc0, int lane, i32x16 (&acc)[2]) {
    constexpr int NG = NT * 8;
    i32x4 b_cur  = load_b(wq8, taps[0], 0, oc0, lane);
    i32x4 a0_cur = load_a(qa, taps[0] < 3 ? 1 : 0, taps[0] % 3 == 0 ? 1 : 0, 0, 0, lane);
    i32x4 a1_cur = load_a(qa, taps[0] < 3 ? 1 : 0, taps[0] % 3 == 0 ? 1 : 0, 0, 1, lane);
    #pragma unroll
    for (int g = 0; g < NG - 1; ++g) {
        const int tap = taps[(g + 1) >> 3];
        const int R = tap < 3 ? 1 : 0;
        const int S = (tap % 3 == 0) ? 1 : 0;
        const int ks = (g + 1) & 7;
        const i32x4 b_nxt  = load_b(wq8, tap, ks, oc0, lane);
        const i32x4 a0_nxt = load_a(qa, R, S, ks, 0, lane);
        const i32x4 a1_nxt = load_a(qa, R, S, ks, 1, lane);
        // swapped: weights are the M-operand -> D has row=oc, col=v
        acc[0] = __builtin_amdgcn_mfma_i32_32x32x32_i8(b_cur, a0_cur, acc[0], 0, 0, 0);
        acc[1] = __builtin_amdgcn_mfma_i32_32x32x32_i8(b_cur, a1_cur, acc[1], 0, 0, 0);
        b_cur = b_nxt; a0_cur = a0_nxt; a1_cur = a1_nxt;
    }
    acc[0] = __builtin_amdgcn_mfma_i32_32x32x32_i8(b_cur, a0_cur, acc[0], 0, 0, 0);
    acc[1] = __builtin_amdgcn_mfma_i32_32x32x32_i8(b_cur, a1_cur, acc[1], 0, 0, 0);
}

__global__ __launch_bounds__(256) void k_conv(
        const float* __restrict__ bias,
        const float* __restrict__ ws, float* __restrict__ out) {
    __shared__ __align__(16) char smem[33792 + 512];
    char*  qa    = smem;
    float* sbias = (float*)(smem + 33792);

    const int tid  = threadIdx.x;
    // bijective XCD swizzle (1024 % 8 == 0): each XCD gets 128 consecutive f
    const int f0   = (blockIdx.x & 7) * 128 + (blockIdx.x >> 3);
    const int b    = f0 >> 6;
    const int u    = f0 & 63;        // output rows 2u, 2u+1
    const int lane = tid & 63;
    const int q    = tid >> 6;       // wave = oc quarter (32 wide), 0..3

    if (tid < 128) sbias[tid] = bias[tid];
    if (tid < 32) {                  // zero pad column v=64 (both r)
        const int r = tid >> 4;
        *(i32x4*)(qa + (r * 66 + 64) * 256 + (tid & 15) * 16) = (i32x4)(0);
    }

    // staging = pure linear copy of pre-quantized, pre-swizzled rows (16 KB each)
    const char* qx = (const char*)(ws + WS_QX);
    #pragma unroll
    for (int r = 0; r < 2; ++r) {
        const int row = u + r;
        i32x4* dst = (i32x4*)(qa + r * 66 * 256);
        if (row < IH) {
            const i32x4* src = (const i32x4*)(qx + (((size_t)b * IH + row) * 64) * 256);
            #pragma unroll
            for (int i = 0; i < 4; ++i)
                dst[i * 256 + tid] = src[i * 256 + tid];
        } else {
            #pragma unroll
            for (int i = 0; i < 4; ++i)
                dst[i * 256 + tid] = (i32x4)(0);
        }
    }
    __syncthreads();                 // the ONLY barrier

    const char* wq8 = (const char*)(ws + WS_WQ8);
    const int oc0 = q * 32 + (lane & 31);
    const float fsc = ws[WS_F];
    const int vv  = lane & 31;
    const int ocq = q * 32 + 4 * (lane >> 5);

    // dense f32x2 NT stores: lane&31 = v, both parities in-lane -> ow {2v, 2v+1}
    auto store_row = [&](const i32x16 (&p0)[2], const i32x16 (&p1)[2], int oh) {
        #pragma unroll
        for (int reg = 0; reg < 16; ++reg) {
            const int oc = ocq + (reg & 3) + 8 * (reg >> 2);
            const float bv = sbias[oc];
            float* rowp = out + (((size_t)(b * OCH + oc)) * OH2 + oh) * OW2;
            #pragma unroll
            for (int m = 0; m < 2; ++m) {
                f32x2 o;
                o.x = fmaf((float)p0[m][reg], fsc, bv);
                o.y = fmaf((float)p1[m][reg], fsc, bv);
                __builtin_nontemporal_store(o, (f32x2*)(rowp + 2 * (m * 32 + vv)));
            }
        }
    };

    i32x16 accP0[2], accP1[2];       // 64 VGPR accumulator budget (spill-free shape)

    // ---- output row 2u: par0 tap{4}, par1 taps{3,5} ----
    accP0[0] = (i32x16)(0); accP0[1] = (i32x16)(0);
    accP1[0] = (i32x16)(0); accP1[1] = (i32x16)(0);
    {
        const int t0[1] = {4};
        gemm_run<1>(qa, wq8, t0, oc0, lane, accP0);
        const int t1[2] = {3, 5};
        gemm_run<2>(qa, wq8, t1, oc0, lane, accP1);
    }
    store_row(accP0, accP1, 2 * u);

    // ---- output row 2u+1: par0 taps{1,7}, par1 taps{0,2,6,8} ----
    accP0[0] = (i32x16)(0); accP0[1] = (i32x16)(0);
    accP1[0] = (i32x16)(0); accP1[1] = (i32x16)(0);
    {
        const int t0[2] = {1, 7};
        gemm_run<2>(qa, wq8, t0, oc0, lane, accP0);
        const int t1[4] = {0, 2, 6, 8};
        gemm_run<4>(qa, wq8, t1, oc0, lane, accP1);
    }
    store_row(accP0, accP1, 2 * u + 1);
}

extern "C" void kernel_launch(void* const* d_in, const int* in_sizes, int n_in,
                              void* d_out, int out_size, void* d_ws, size_t ws_size,
                              hipStream_t stream) {
    const float* x    = (const float*)d_in[0];
    const float* w    = (const float*)d_in[1];
    const float* bias = (const float*)d_in[2];
    float* ws  = (float*)d_ws;
    float* out = (float*)d_out;

    k_channel_scales<<<dim3(256, 8), 256, 0, stream>>>(x, w, ws);
    k_quant<<<1312, 256, 0, stream>>>(x, w, ws);
    k_conv<<<1024, 256, 0, stream>>>(bias, ws, out);
}